// Round 9
// baseline (404.973 us; speedup 1.0000x reference)
//
#include <hip/hip_runtime.h>
#include <hip/hip_fp16.h>
#include <hip/hip_cooperative_groups.h>
#include <math.h>

namespace cg = cooperative_groups;

// Problem constants
#define N_  8
#define C_  256
#define G_  8
#define CG_ 32
#define K_  9
#define H_  64
#define W_  64
#define L_  (H_*W_)      // 4096
#define OM_ 216          // G*K*3
#define OMP_ 256         // padded om row stride (fp32), groups packed at g*27

using frag_ab = __attribute__((ext_vector_type(8))) short;   // 8 bf16
using frag_cd = __attribute__((ext_vector_type(4))) float;   // 4 fp32

__device__ __forceinline__ unsigned short f2bf(float f) {    // RNE fp32->bf16
    unsigned int u = __float_as_uint(f);
    u += 0x7FFFu + ((u >> 16) & 1u);
    return (unsigned short)(u >> 16);
}
__device__ __forceinline__ unsigned short f2h(float f) {     // RNE fp32->fp16
    return __half_as_ushort(__float2half(f));
}

__device__ __forceinline__ void gld16(const void* g, void* l) {
    __builtin_amdgcn_global_load_lds((const __attribute__((address_space(1))) void*)g,
                                     (__attribute__((address_space(3))) void*)l, 16, 0, 0);
}

// bilinear tap -> (4 weights, 4 row-offsets<<9)
__device__ __forceinline__ void tapcalc(int l, int k, float offy, float offx, float mk,
                                        float4& wq, uint4& sq) {
    const int y = l >> 6, xp = l & 63;
    float py = (float)(y + k / 3 - 1) + offy;
    float px = (float)(xp + k % 3 - 1) + offx;
    float fy = floorf(py), fx = floorf(px);
    float ty = py - fy, tx = px - fx;
    int y0 = (int)fy, x0i = (int)fx;
    int y1 = y0 + 1, x1 = x0i + 1;
    float vy0 = ((unsigned)y0 < (unsigned)H_) ? 1.f : 0.f;
    float vy1 = ((unsigned)y1 < (unsigned)H_) ? 1.f : 0.f;
    float vx0 = ((unsigned)x0i < (unsigned)W_) ? 1.f : 0.f;
    float vx1 = ((unsigned)x1 < (unsigned)W_) ? 1.f : 0.f;
    int cy0 = min(max(y0, 0), H_ - 1), cy1 = min(max(y1, 0), H_ - 1);
    int cx0 = min(max(x0i, 0), W_ - 1), cx1 = min(max(x1, 0), W_ - 1);
    wq = make_float4(mk * (1.f - ty) * (1.f - tx) * vy0 * vx0,
                     mk * (1.f - ty) * tx         * vy0 * vx1,
                     mk * ty         * (1.f - tx) * vy1 * vx0,
                     mk * ty         * tx         * vy1 * vx1);
    sq = make_uint4((unsigned)((cy0 * W_ + cx0) << 9),
                    (unsigned)((cy0 * W_ + cx1) << 9),
                    (unsigned)((cy1 * W_ + cx0) << 9),
                    (unsigned)((cy1 * W_ + cx1) << 9));
}

// ===========================================================================
// Phase bodies (shared by the fused cooperative kernel and the 3-kernel
// fallback). Per-thread code is byte-identical to the R6-proven kernels.
// ===========================================================================

// ---- prep body: depthwise 3x3 conv + transpose + bf16 convert (R4) --------
__device__ __forceinline__ void prep_body(
    int u, int tid,
    const float* __restrict__ x, const float* __restrict__ w, const float* __restrict__ b,
    const float* __restrict__ vp_w, const float* __restrict__ om_w,
    const float* __restrict__ om_b, const float* __restrict__ op_w,
    unsigned short* __restrict__ xb, unsigned short* __restrict__ omb,
    unsigned short* __restrict__ vp_wb, unsigned short* __restrict__ om_wb,
    float* __restrict__ om_bp, unsigned short* __restrict__ op_wb,
    float (*xs)[32][66], unsigned short (*os)[64][40])
{
    const int bx = u & 7, by = (u >> 3) & 15, n = u >> 7;
    const int y0 = by * 4, c0 = bx * 32;
    for (int i = tid; i < 384; i += 256) {
        int r = i / 64, c = (i / 2) % 32, e = i & 1;
        xs[r][c][e * 65] = 0.f;
    }
    const float* xbase = x + ((size_t)n * C_ + c0) * L_;
    for (int i = tid; i < 6 * 32 * 16; i += 256) {   // 6 rows x 32 ch x 16 float4
        int r = i >> 9, rem = i & 511, c = rem >> 4, x4 = (rem & 15) * 4;
        int yy = y0 + r - 1;
        float4 v = make_float4(0.f, 0.f, 0.f, 0.f);
        if ((unsigned)yy < (unsigned)H_) v = *(const float4*)(xbase + (size_t)c * L_ + yy * W_ + x4);
        xs[r][c][1 + x4] = v.x; xs[r][c][2 + x4] = v.y;
        xs[r][c][3 + x4] = v.z; xs[r][c][4 + x4] = v.w;
    }
    __syncthreads();

    const int c = tid & 31, x0 = (tid >> 5) * 8;
    float wv[9];
#pragma unroll
    for (int i = 0; i < 9; i++) wv[i] = w[(c0 + c) * 9 + i];
    const float bias = b[c0 + c];
    const int l = tid >> 2, c8 = (tid & 3) * 8;

    for (int rr = 0; rr < 4; rr++) {
        float o[8];
#pragma unroll
        for (int j = 0; j < 8; j++) o[j] = bias;
#pragma unroll
        for (int r = 0; r < 3; r++) {
            float v[10];
#pragma unroll
            for (int d = 0; d < 10; d++) v[d] = xs[rr + r][c][x0 + d];
#pragma unroll
            for (int j = 0; j < 8; j++)
                o[j] += wv[r * 3] * v[j] + wv[r * 3 + 1] * v[j + 1] + wv[r * 3 + 2] * v[j + 2];
        }
#pragma unroll
        for (int j = 0; j < 8; j++) {
            os[0][x0 + j][c] = f2bf(xs[rr + 1][c][1 + x0 + j]);
            os[1][x0 + j][c] = f2bf(o[j]);
        }
        __syncthreads();
        uint4 va = *(const uint4*)&os[0][l][c8];
        uint4 vc = *(const uint4*)&os[1][l][c8];
        // channel-tiled: [n][kb][l][32]; wave store = contiguous 1 KB
        size_t dst = (((size_t)n * 8 + bx) * L_ + (y0 + rr) * W_ + l) * 32 + c8;
        *(uint4*)(xb + dst) = va;
        *(uint4*)(omb + dst) = vc;
        __syncthreads();   // os safe to overwrite next row
    }

    // Weight conversion: n==0 units (u<128); 2 chunks each.
    if (n == 0) {
        int base = (bx + 8 * by) * 256 + tid;   // 0..32767
#pragma unroll
        for (int rep2 = 0; rep2 < 2; rep2++) {
            int idx = base + rep2 * 32768;       // 0..65535
            vp_wb[idx] = f2bf(vp_w[idx]);
            op_wb[idx] = f2bf(op_w[idx]);
            om_wb[idx] = (idx < OM_ * C_) ? f2bf(om_w[idx]) : (unsigned short)0;
        }
        if (base < OMP_) om_bp[base] = (base < OM_) ? om_b[base] : 0.f;
    }
}

// ---- gemm12 body: full-N 128x256 LDS-staged MFMA GEMM (R6, proven) --------
__device__ __forceinline__ void gemm12_body(
    int bx, int which, int tid,
    const unsigned short* __restrict__ xb, const unsigned short* __restrict__ omb,
    const unsigned short* __restrict__ vp_wb, const unsigned short* __restrict__ om_wb,
    const float* __restrict__ vp_b, const float* __restrict__ om_bp,
    unsigned short* __restrict__ valueb, float* __restrict__ omf,
    unsigned short* As, unsigned short* Bs)
{
    const unsigned short* A = which ? omb : xb;
    const unsigned short* B = which ? om_wb : vp_wb;
    const float* bias = which ? om_bp : vp_b;
    const long i0 = (long)bx * 128;
    const int nA = (int)(i0 >> 12);
    const int lofs = (int)(i0 & 4095);
    const int wave = tid >> 6, lane = tid & 63;
    const int iw = (wave & 1) * 64, jw = (wave >> 1) * 128;
    const int lm = lane & 15, kq = lane >> 4;
    const int srow = tid >> 2, scol = (tid & 3) * 8;

    frag_cd acc[4][8];
#pragma unroll
    for (int a = 0; a < 4; a++)
#pragma unroll
        for (int c = 0; c < 8; c++) acc[a][c] = (frag_cd){0.f, 0.f, 0.f, 0.f};

    for (int k0 = 0; k0 < C_; k0 += 32) {
        const unsigned short* ga0 = A + (((size_t)nA * 8 + (k0 >> 5)) * L_ + lofs + srow) * 32 + scol;
        const unsigned short* gb0 = B + (long)srow * C_ + k0 + scol;
        gld16(ga0,             As + tid * 8);
        gld16(ga0 + 64 * 32,   As + 2048 + tid * 8);
        gld16(gb0,             Bs + tid * 8);
        gld16(gb0 + 64 * C_,   Bs + 2048 + tid * 8);
        gld16(gb0 + 128 * C_,  Bs + 4096 + tid * 8);
        gld16(gb0 + 192 * C_,  Bs + 6144 + tid * 8);
        __syncthreads();
        frag_ab af[4], bfr[8];
#pragma unroll
        for (int mi = 0; mi < 4; mi++)
            af[mi] = *(const frag_ab*)&As[(iw + mi * 16 + lm) * 32 + kq * 8];
#pragma unroll
        for (int ni = 0; ni < 8; ni++)
            bfr[ni] = *(const frag_ab*)&Bs[(jw + ni * 16 + lm) * 32 + kq * 8];
#pragma unroll
        for (int mi = 0; mi < 4; mi++)
#pragma unroll
            for (int ni = 0; ni < 8; ni++)
                acc[mi][ni] = __builtin_amdgcn_mfma_f32_16x16x32_bf16(af[mi], bfr[ni], acc[mi][ni], 0, 0, 0);
        __syncthreads();
    }

    float bv[8];
#pragma unroll
    for (int ni = 0; ni < 8; ni++)
        bv[ni] = bias[jw + ni * 16 + lm];

    const long ibase = i0 + iw + kq * 4;
    const int jbase = jw + lm;
#pragma unroll
    for (int mi = 0; mi < 4; mi++) {
#pragma unroll
        for (int ni = 0; ni < 8; ni++) {
            int jj = jbase + ni * 16;
#pragma unroll
            for (int r = 0; r < 4; r++) {
                long i = ibase + mi * 16 + r;
                float v = acc[mi][ni][r] + bv[ni];
                if (which)
                    omf[i * OMP_ + jj] = v;
                else
                    valueb[i * C_ + jj] = f2h(v);   // FP16 value (fma_mix gather)
            }
        }
    }
}

// ---- samplegemm body: barrier-free rep loop + MFMA phase C (R6, proven) ---
__device__ __forceinline__ void samplegemm_body(
    int n, int l0, int tid,
    const unsigned short* __restrict__ value, const float* __restrict__ om,
    const unsigned short* __restrict__ opw, float* __restrict__ out,
    unsigned short* interm, float (*ombuf)[224], float4 (*wgt)[9], uint4 (*soff)[9])
{
    const int wave = tid >> 6, lane = tid & 63;
    const int lp = tid >> 2;            // pair 0..63; wave w owns lp 16w..16w+15
    const int g = lp & 7;
    const int c8i = tid & 3;
    const int slot = tid & 31;          // = g*4 + c8i
    const char* vbase = (const char*)(value + (size_t)n * L_ * C_);
    const char* vb = vbase + (size_t)(g * CG_ + c8i * 8) * 2;

    const float* omn = om + (size_t)n * L_ * OMP_;
    float* obase = &ombuf[2 * wave][0];                 // wave-uniform dest base

    const int s0row = (lane < 56) ? 0 : 1;              // 0 -> p0, 1 -> p1
    const int s0idx = (lane < 56) ? lane : (lane - 56);

#define STAGE_OM(REP) { \
        const float* r0_ = omn + (size_t)(l0 + (REP) * 8 + 2 * wave) * OMP_; \
        gld16(r0_ + (size_t)s0row * OMP_ + s0idx * 4, obase); \
        if (lane < 48) gld16(r0_ + OMP_ + (8 + lane) * 4, (char*)obase + 1024); }

    STAGE_OM(0)

    for (int rep = 0; rep < 8; rep++) {
        asm volatile("s_waitcnt vmcnt(0)" ::: "memory");
        // --- tap compute: 144 items (16 pairs x 9 taps) over 64 lanes ---
#pragma unroll
        for (int j = 0; j < 3; j++) {
            if (!(j == 2 && lane >= 16)) {
                int it = lane + j * 64;                  // 0..143
                int pl_loc = it / 9, k = it - pl_loc * 9;
                int pl = wave * 16 + pl_loc;
                int pic = pl >> 3;                       // pixel-in-chunk 0..7
                const float* ob2 = &ombuf[pic][(pl & 7) * 27];
                float offy = ob2[2 * k], offx = ob2[2 * k + 1], mk = ob2[18 + k];
                float4 wq; uint4 sq;
                tapcalc(l0 + rep * 8 + pic, k, offy, offx, mk, wq, sq);
                wgt[pl][k] = wq; soff[pl][k] = sq;
            }
        }
        asm volatile("" ::: "memory");
        if (rep < 7) STAGE_OM(rep + 1)
        asm volatile("" ::: "memory");
        // --- gather ---
        const int p = rep * 8 + (lp >> 3);
        float acc[8] = {0.f, 0.f, 0.f, 0.f, 0.f, 0.f, 0.f, 0.f};
#pragma unroll
        for (int k = 0; k < K_; k++) {
            float4 wk = wgt[lp][k];
            uint4  ok = soff[lp][k];
            const uint4 v00 = *(const uint4*)(vb + ok.x);
            const uint4 v01 = *(const uint4*)(vb + ok.y);
            const uint4 v10 = *(const uint4*)(vb + ok.z);
            const uint4 v11 = *(const uint4*)(vb + ok.w);
#define ACC8(V, WW) { \
            const __half2* h_ = (const __half2*)&V; \
            acc[0] += WW * __half2float(h_[0].x); acc[1] += WW * __half2float(h_[0].y); \
            acc[2] += WW * __half2float(h_[1].x); acc[3] += WW * __half2float(h_[1].y); \
            acc[4] += WW * __half2float(h_[2].x); acc[5] += WW * __half2float(h_[2].y); \
            acc[6] += WW * __half2float(h_[3].x); acc[7] += WW * __half2float(h_[3].y); }
            ACC8(v00, wk.x) ACC8(v01, wk.y) ACC8(v10, wk.z) ACC8(v11, wk.w)
#undef ACC8
        }
        uint4 pk;
        unsigned short* ps = (unsigned short*)&pk;
#pragma unroll
        for (int i = 0; i < 8; i++) ps[i] = f2bf(acc[i]);
        int phys = slot ^ (p & 7);
        *(uint4*)&interm[p * 256 + phys * 8] = pk;      // wave-private rows
    }
#undef STAGE_OM
    __syncthreads();   // interm ready for phase C

    // --- Phase C: per wave 64q x 64px, 4x4 frags, K=256 in 8 steps ---
    const int lm = lane & 15, kq = lane >> 4;
    const int q0w = wave * 64;
    frag_cd acc2[4][4];
#pragma unroll
    for (int a = 0; a < 4; a++)
#pragma unroll
        for (int c = 0; c < 4; c++) acc2[a][c] = (frag_cd){0.f, 0.f, 0.f, 0.f};

    for (int k0 = 0; k0 < C_; k0 += 32) {
        frag_ab af[4], bfr[4];
#pragma unroll
        for (int mi = 0; mi < 4; mi++)
            af[mi] = *(const frag_ab*)(opw + (size_t)(q0w + mi * 16 + lm) * C_ + k0 + kq * 8);
#pragma unroll
        for (int ni = 0; ni < 4; ni++) {
            int pxr = ni * 16 + lm;
            int phys = (k0 / 8 + kq) ^ (pxr & 7);
            bfr[ni] = *(const frag_ab*)&interm[pxr * 256 + phys * 8];
        }
#pragma unroll
        for (int mi = 0; mi < 4; mi++)
#pragma unroll
            for (int ni = 0; ni < 4; ni++)
                acc2[mi][ni] = __builtin_amdgcn_mfma_f32_16x16x32_bf16(af[mi], bfr[ni], acc2[mi][ni], 0, 0, 0);
    }

    float* ob = out + (size_t)n * C_ * L_ + l0;
#pragma unroll
    for (int mi = 0; mi < 4; mi++) {
#pragma unroll
        for (int ni = 0; ni < 4; ni++) {
            int pxr = ni * 16 + lm;
#pragma unroll
            for (int r = 0; r < 4; r++) {
                int q = q0w + mi * 16 + kq * 4 + r;
                ob[(size_t)q * L_ + pxr] = acc2[mi][ni][r];
            }
        }
    }
}

// ===========================================================================
// FUSED cooperative kernel: 512 blocks x 256 threads, 2 blocks/CU (LDS 60928
// -> exactly 512 co-resident). Two grid.sync()s replace two kernel
// boundaries (inferred >= ~34 us of inter-dispatch overhead: total minus
// samplegemm ~ 122 us while no prep/gemm12 dispatch exceeds 44 us).
// Block-id decodes reproduce every proven mapping, incl. samplegemm's XCD
// pinning (n = bid&7) and gemm12's XCD spread (bx%8).
// ===========================================================================
__global__ __launch_bounds__(256, 2) void fused_kernel(
    const float* __restrict__ x, const float* __restrict__ dw_w, const float* __restrict__ dw_b,
    const float* __restrict__ om_w, const float* __restrict__ om_b,
    const float* __restrict__ vp_w, const float* __restrict__ vp_b,
    const float* __restrict__ op_w,
    unsigned short* __restrict__ xb, unsigned short* __restrict__ omb,
    unsigned short* __restrict__ valueb, float* __restrict__ omf,
    unsigned short* __restrict__ vp_wb, unsigned short* __restrict__ om_wb,
    unsigned short* __restrict__ op_wb, float* __restrict__ om_bp,
    float* __restrict__ out)
{
    __shared__ __align__(16) char smem[60928];   // union of all 3 phase layouts
    const int bid = blockIdx.x;
    const int tid = threadIdx.x;
    cg::grid_group grid = cg::this_grid();

    // ---- Phase 1: prep (2 units per block; units 0..1023) ----
    {
        float (*xs)[32][66] = (float(*)[32][66])smem;                              // 50688 B
        unsigned short (*os)[64][40] = (unsigned short(*)[64][40])(smem + 50688);  // 10240 B
        prep_body(bid * 2,     tid, x, dw_w, dw_b, vp_w, om_w, om_b, op_w,
                  xb, omb, vp_wb, om_wb, om_bp, op_wb, xs, os);
        prep_body(bid * 2 + 1, tid, x, dw_w, dw_b, vp_w, om_w, om_b, op_w,
                  xb, omb, vp_wb, om_wb, om_bp, op_wb, xs, os);
    }
    __threadfence();
    grid.sync();

    // ---- Phase 2: gemm12 (bx = bid&255, which = bid>>8) ----
    {
        unsigned short* As = (unsigned short*)smem;            // 8192 B
        unsigned short* Bs = (unsigned short*)(smem + 8192);   // 16384 B
        gemm12_body(bid & 255, bid >> 8, tid, xb, omb, vp_wb, om_wb,
                    vp_b, om_bp, valueb, omf, As, Bs);
    }
    __threadfence();
    grid.sync();

    // ---- Phase 3: samplegemm (n = bid&7 XCD-pinned, l0 = (bid>>3)*64) ----
    {
        unsigned short* interm = (unsigned short*)smem;               // 32768 B
        float (*ombuf)[224] = (float(*)[224])(smem + 32768);          //  7168 B
        float4 (*wgt)[9]    = (float4(*)[9])(smem + 39936);           //  9216 B
        uint4 (*soff)[9]    = (uint4(*)[9])(smem + 49152);            //  9216 B
        samplegemm_body(bid & 7, (bid >> 3) * 64, tid, valueb, omf, op_wb, out,
                        interm, ombuf, wgt, soff);
    }
}

// ===========================================================================
// Fallback standalone kernels (exact R6-proven configuration) — used only if
// the cooperative launch is rejected (e.g., not supported under capture).
// ===========================================================================
__global__ __launch_bounds__(256) void prep_kernel(
    const float* __restrict__ x, const float* __restrict__ w, const float* __restrict__ b,
    const float* __restrict__ vp_w, const float* __restrict__ om_w,
    const float* __restrict__ om_b, const float* __restrict__ op_w,
    unsigned short* __restrict__ xb, unsigned short* __restrict__ omb,
    unsigned short* __restrict__ vp_wb, unsigned short* __restrict__ om_wb,
    float* __restrict__ om_bp, unsigned short* __restrict__ op_wb)
{
    __shared__ float xs[6][32][66];
    __shared__ __align__(16) unsigned short os[2][64][40];
    int u = blockIdx.x + 8 * blockIdx.y + 128 * blockIdx.z;
    prep_body(u, threadIdx.x, x, w, b, vp_w, om_w, om_b, op_w,
              xb, omb, vp_wb, om_wb, om_bp, op_wb, xs, os);
}

__global__ __launch_bounds__(256, 2) void gemm12_kernel(
    const unsigned short* __restrict__ xb, const unsigned short* __restrict__ omb,
    const unsigned short* __restrict__ vp_wb, const unsigned short* __restrict__ om_wb,
    const float* __restrict__ vp_b, const float* __restrict__ om_bp,
    unsigned short* __restrict__ valueb, float* __restrict__ omf)
{
    __shared__ unsigned short As[128 * 32];
    __shared__ unsigned short Bs[256 * 32];
    gemm12_body(blockIdx.x, blockIdx.z, threadIdx.x, xb, omb, vp_wb, om_wb,
                vp_b, om_bp, valueb, omf, As, Bs);
}

__global__ __launch_bounds__(256, 2) void samplegemm_kernel(
    const unsigned short* __restrict__ value, const float* __restrict__ om,
    const unsigned short* __restrict__ opw, float* __restrict__ out)
{
    __shared__ __align__(16) unsigned short interm[64 * 256];
    __shared__ __align__(16) float ombuf[8][224];
    __shared__ float4 wgt[64][9];
    __shared__ uint4  soff[64][9];
    samplegemm_body(blockIdx.x, blockIdx.y * 64, threadIdx.x, value, om, opw, out,
                    interm, ombuf, wgt, soff);
}

// ---------------------------------------------------------------------------
// Workspace layout (84,280,320 B total):
//   [0,        16777216)  xb  [n][kb][l][32] bf16 (channel-tiled)
//   [16777216, 33554432)  omb [n][kb][l][32] bf16 (channel-tiled)
//   [33554432, 50331648)  valueb (n,L,C) FP16
//   [50331648, 83886080)  omf (n,L,256) fp32 (full rows, pad cols zero)
//   [83886080, ...)       vp_wb, om_wb, op_wb bf16 (128KB each), om_bp fp32
// ---------------------------------------------------------------------------
extern "C" void kernel_launch(void* const* d_in, const int* in_sizes, int n_in,
                              void* d_out, int out_size, void* d_ws, size_t ws_size,
                              hipStream_t stream) {
    const float* x    = (const float*)d_in[0];
    const float* dw_w = (const float*)d_in[1];
    const float* dw_b = (const float*)d_in[2];
    const float* om_w = (const float*)d_in[3];
    const float* om_b = (const float*)d_in[4];
    const float* vp_w = (const float*)d_in[5];
    const float* vp_b = (const float*)d_in[6];
    const float* op_w = (const float*)d_in[7];
    float* out = (float*)d_out;

    char* ws = (char*)d_ws;
    unsigned short* xb      = (unsigned short*)(ws);
    unsigned short* omb     = (unsigned short*)(ws + 16777216);
    unsigned short* valueb  = (unsigned short*)(ws + 33554432);
    float*          omf     = (float*)(ws + 50331648);
    unsigned short* vp_wb   = (unsigned short*)(ws + 83886080);
    unsigned short* om_wb   = (unsigned short*)(ws + 84017152);
    unsigned short* op_wb   = (unsigned short*)(ws + 84148224);
    float*          om_bp   = (float*)(ws + 84279296);

    void* args[] = {
        (void*)&x, (void*)&dw_w, (void*)&dw_b, (void*)&om_w, (void*)&om_b,
        (void*)&vp_w, (void*)&vp_b, (void*)&op_w,
        (void*)&xb, (void*)&omb, (void*)&valueb, (void*)&omf,
        (void*)&vp_wb, (void*)&om_wb, (void*)&op_wb, (void*)&om_bp,
        (void*)&out
    };
    hipError_t err = hipLaunchCooperativeKernel((void*)fused_kernel,
                                                dim3(512), dim3(256), args, 0, stream);
    if (err != hipSuccess) {
        // Fallback: 3-kernel path (R6-proven configuration).
        prep_kernel<<<dim3(C_ / 32, H_ / 4, N_), 256, 0, stream>>>(
            x, dw_w, dw_b, vp_w, om_w, om_b, op_w,
            xb, omb, vp_wb, om_wb, om_bp, op_wb);
        gemm12_kernel<<<dim3(256, 1, 2), 256, 0, stream>>>(
            xb, omb, vp_wb, om_wb, vp_b, om_bp, valueb, omf);
        samplegemm_kernel<<<dim3(N_, L_ / 64), 256, 0, stream>>>(valueb, omf, op_wb, out);
    }
}

// Round 10
// 164.775 us; speedup vs baseline: 2.4577x; 2.4577x over previous
//
#include <hip/hip_runtime.h>
#include <hip/hip_fp16.h>
#include <math.h>

// Problem constants
#define N_  8
#define C_  256
#define G_  8
#define CG_ 32
#define K_  9
#define H_  64
#define W_  64
#define L_  (H_*W_)      // 4096
#define OM_ 216          // G*K*3
#define OMP_ 256         // padded om row stride (fp32), groups packed at g*27

using frag_ab = __attribute__((ext_vector_type(8))) short;   // 8 bf16
using frag_cd = __attribute__((ext_vector_type(4))) float;   // 4 fp32

__device__ __forceinline__ unsigned short f2bf(float f) {    // RNE fp32->bf16
    unsigned int u = __float_as_uint(f);
    u += 0x7FFFu + ((u >> 16) & 1u);
    return (unsigned short)(u >> 16);
}
__device__ __forceinline__ unsigned short f2h(float f) {     // RNE fp32->fp16
    return __half_as_ushort(__float2half(f));
}

__device__ __forceinline__ void gld16(const void* g, void* l) {
    __builtin_amdgcn_global_load_lds((const __attribute__((address_space(1))) void*)g,
                                     (__attribute__((address_space(3))) void*)l, 16, 0, 0);
}

// bilinear tap -> (4 weights, 4 row-offsets<<9)
__device__ __forceinline__ void tapcalc(int l, int k, float offy, float offx, float mk,
                                        float4& wq, uint4& sq) {
    const int y = l >> 6, xp = l & 63;
    float py = (float)(y + k / 3 - 1) + offy;
    float px = (float)(xp + k % 3 - 1) + offx;
    float fy = floorf(py), fx = floorf(px);
    float ty = py - fy, tx = px - fx;
    int y0 = (int)fy, x0i = (int)fx;
    int y1 = y0 + 1, x1 = x0i + 1;
    float vy0 = ((unsigned)y0 < (unsigned)H_) ? 1.f : 0.f;
    float vy1 = ((unsigned)y1 < (unsigned)H_) ? 1.f : 0.f;
    float vx0 = ((unsigned)x0i < (unsigned)W_) ? 1.f : 0.f;
    float vx1 = ((unsigned)x1 < (unsigned)W_) ? 1.f : 0.f;
    int cy0 = min(max(y0, 0), H_ - 1), cy1 = min(max(y1, 0), H_ - 1);
    int cx0 = min(max(x0i, 0), W_ - 1), cx1 = min(max(x1, 0), W_ - 1);
    wq = make_float4(mk * (1.f - ty) * (1.f - tx) * vy0 * vx0,
                     mk * (1.f - ty) * tx         * vy0 * vx1,
                     mk * ty         * (1.f - tx) * vy1 * vx0,
                     mk * ty         * tx         * vy1 * vx1);
    sq = make_uint4((unsigned)((cy0 * W_ + cx0) << 9),
                    (unsigned)((cy0 * W_ + cx1) << 9),
                    (unsigned)((cy1 * W_ + cx0) << 9),
                    (unsigned)((cy1 * W_ + cx1) << 9));
}

// ---------------------------------------------------------------------------
// Fused prep: depthwise 3x3 conv + transpose + bf16 convert. 4 output rows
// per block (6 input rows loaded once -> 1.5x halo). Exact R4/R6 (proven).
// grid (C/32, H/4, N), block 256.
// ---------------------------------------------------------------------------
__global__ __launch_bounds__(256) void prep_kernel(const float* __restrict__ x,
                                                   const float* __restrict__ w,
                                                   const float* __restrict__ b,
                                                   const float* __restrict__ vp_w,
                                                   const float* __restrict__ om_w,
                                                   const float* __restrict__ om_b,
                                                   const float* __restrict__ op_w,
                                                   unsigned short* __restrict__ xb,
                                                   unsigned short* __restrict__ omb,
                                                   unsigned short* __restrict__ vp_wb,
                                                   unsigned short* __restrict__ om_wb,
                                                   float* __restrict__ om_bp,
                                                   unsigned short* __restrict__ op_wb) {
    const int n = blockIdx.z, y0 = blockIdx.y * 4, c0 = blockIdx.x * 32;
    const int tid = threadIdx.x;
    __shared__ float xs[6][32][66];                          // 50.7 KB
    __shared__ __align__(16) unsigned short os[2][64][40];   // 10.2 KB (per-row reuse)
    for (int i = tid; i < 384; i += 256) {
        int r = i / 64, c = (i / 2) % 32, e = i & 1;
        xs[r][c][e * 65] = 0.f;
    }
    const float* xbase = x + ((size_t)n * C_ + c0) * L_;
    for (int i = tid; i < 6 * 32 * 16; i += 256) {   // 6 rows x 32 ch x 16 float4
        int r = i >> 9, rem = i & 511, c = rem >> 4, x4 = (rem & 15) * 4;
        int yy = y0 + r - 1;
        float4 v = make_float4(0.f, 0.f, 0.f, 0.f);
        if ((unsigned)yy < (unsigned)H_) v = *(const float4*)(xbase + (size_t)c * L_ + yy * W_ + x4);
        xs[r][c][1 + x4] = v.x; xs[r][c][2 + x4] = v.y;
        xs[r][c][3 + x4] = v.z; xs[r][c][4 + x4] = v.w;
    }
    __syncthreads();

    const int c = tid & 31, x0 = (tid >> 5) * 8;
    float wv[9];
#pragma unroll
    for (int i = 0; i < 9; i++) wv[i] = w[(c0 + c) * 9 + i];
    const float bias = b[c0 + c];
    const int l = tid >> 2, c8 = (tid & 3) * 8;

    for (int rr = 0; rr < 4; rr++) {
        float o[8];
#pragma unroll
        for (int j = 0; j < 8; j++) o[j] = bias;
#pragma unroll
        for (int r = 0; r < 3; r++) {
            float v[10];
#pragma unroll
            for (int d = 0; d < 10; d++) v[d] = xs[rr + r][c][x0 + d];
#pragma unroll
            for (int j = 0; j < 8; j++)
                o[j] += wv[r * 3] * v[j] + wv[r * 3 + 1] * v[j + 1] + wv[r * 3 + 2] * v[j + 2];
        }
#pragma unroll
        for (int j = 0; j < 8; j++) {
            os[0][x0 + j][c] = f2bf(xs[rr + 1][c][1 + x0 + j]);
            os[1][x0 + j][c] = f2bf(o[j]);
        }
        __syncthreads();
        uint4 va = *(const uint4*)&os[0][l][c8];
        uint4 vc = *(const uint4*)&os[1][l][c8];
        // channel-tiled: [n][kb][l][32]; wave store = contiguous 1 KB
        size_t dst = (((size_t)n * 8 + blockIdx.x) * L_ + (y0 + rr) * W_ + l) * 32 + c8;
        *(uint4*)(xb + dst) = va;
        *(uint4*)(omb + dst) = vc;
        __syncthreads();   // os safe to overwrite next row
    }

    // Weight conversion: n==0 blocks = 8x16 = 128 blocks; 2 chunks each.
    if (n == 0) {
        int base = (blockIdx.x + 8 * blockIdx.y) * 256 + tid;   // 0..32767
#pragma unroll
        for (int rep2 = 0; rep2 < 2; rep2++) {
            int idx = base + rep2 * 32768;                       // 0..65535
            vp_wb[idx] = f2bf(vp_w[idx]);
            op_wb[idx] = f2bf(op_w[idx]);
            om_wb[idx] = (idx < OM_ * C_) ? f2bf(om_w[idx]) : (unsigned short)0;
        }
        if (base < OMP_) om_bp[base] = (base < OM_) ? om_b[base] : 0.f;
    }
}

// ---------------------------------------------------------------------------
// Merged GEMM1+GEMM2, round 10: A-DIRECT + double-buffered B-only staging.
//
// R8 verified A-direct frags from channel-tiled A are correct and each wave
// load is 1 KB fully contiguous (its regression was B-scatter only). R6
// verified B via global_load_lds. Combined: per K-step
//   vmcnt(0) -> barrier -> issue STAGE_B(next buf) -> A-direct loads +
//   B ds_reads -> 32 MFMA.
// vs R6: As LDS round-trip gone, barriers 16 -> 8, B staging overlaps MFMA
// (T3-minimum). LDS 32 KB (Bs x2), ~190 VGPR, LB(256,2).
// z=0: D=valueb fp16; z=1: D=omf fp32. grid (256,1,2), block 256 (4 waves).
// ---------------------------------------------------------------------------
__global__ __launch_bounds__(256, 2) void gemm12_kernel(const unsigned short* __restrict__ xb,
                                                        const unsigned short* __restrict__ omb,
                                                        const unsigned short* __restrict__ vp_wb,
                                                        const unsigned short* __restrict__ om_wb,
                                                        const float* __restrict__ vp_b,
                                                        const float* __restrict__ om_bp,
                                                        unsigned short* __restrict__ valueb,
                                                        float* __restrict__ omf) {
    __shared__ unsigned short Bs[2][256 * 32];   // 32 KB double-buffered B
    const int which = blockIdx.z;
    const unsigned short* A = which ? omb : xb;
    const unsigned short* B = which ? om_wb : vp_wb;
    const float* bias = which ? om_bp : vp_b;
    const int tid = threadIdx.x;
    const long i0 = (long)blockIdx.x * 128;
    const int nA = (int)(i0 >> 12);          // batch index (128-row blocks never straddle n)
    const int lofs = (int)(i0 & 4095);
    const int wave = tid >> 6, lane = tid & 63;
    const int iw = (wave & 1) * 64, jw = (wave >> 1) * 128;
    const int lm = lane & 15, kq = lane >> 4;
    const int srow = tid >> 2, scol = (tid & 3) * 8;

    frag_cd acc[4][8];
#pragma unroll
    for (int a = 0; a < 4; a++)
#pragma unroll
        for (int c = 0; c < 8; c++) acc[a][c] = (frag_cd){0.f, 0.f, 0.f, 0.f};

    // A-direct lane base (R8-verified): frag = 1 KB contiguous per wave
    const unsigned short* Abase = A + (((size_t)nA * 8) * L_ + lofs + iw + lm) * 32 + kq * 8;
    // B staging source (R6-verified): per-lane row srow, cols scol..scol+7
    const unsigned short* gb0 = B + (long)srow * C_ + scol;

#define STAGE_B(KS, BUF) { \
        const unsigned short* gb_ = gb0 + (KS) * 32; \
        gld16(gb_,             Bs[BUF] + tid * 8); \
        gld16(gb_ + 64 * C_,   Bs[BUF] + 2048 + tid * 8); \
        gld16(gb_ + 128 * C_,  Bs[BUF] + 4096 + tid * 8); \
        gld16(gb_ + 192 * C_,  Bs[BUF] + 6144 + tid * 8); }

    STAGE_B(0, 0)

#pragma unroll
    for (int ks = 0; ks < 8; ks++) {     // k0 = ks*32
        const int buf = ks & 1;
        // drain my wave's gld16 into Bs[buf], then publish across waves
        asm volatile("s_waitcnt vmcnt(0)" ::: "memory");
        __syncthreads();
        if (ks < 7) STAGE_B(ks + 1, buf ^ 1)   // overlaps with MFMA below
        frag_ab af[4], bfr[8];
#pragma unroll
        for (int mi = 0; mi < 4; mi++)
            af[mi] = *(const frag_ab*)(Abase + ((size_t)ks * L_ + mi * 16) * 32);
#pragma unroll
        for (int ni = 0; ni < 8; ni++)
            bfr[ni] = *(const frag_ab*)&Bs[buf][(jw + ni * 16 + lm) * 32 + kq * 8];
#pragma unroll
        for (int mi = 0; mi < 4; mi++)
#pragma unroll
            for (int ni = 0; ni < 8; ni++)
                acc[mi][ni] = __builtin_amdgcn_mfma_f32_16x16x32_bf16(af[mi], bfr[ni], acc[mi][ni], 0, 0, 0);
    }
#undef STAGE_B

    float bv[8];
#pragma unroll
    for (int ni = 0; ni < 8; ni++)
        bv[ni] = bias[jw + ni * 16 + lm];

    const long ibase = i0 + iw + kq * 4;
    const int jbase = jw + lm;
#pragma unroll
    for (int mi = 0; mi < 4; mi++) {
#pragma unroll
        for (int ni = 0; ni < 8; ni++) {
            int jj = jbase + ni * 16;
#pragma unroll
            for (int r = 0; r < 4; r++) {
                long i = ibase + mi * 16 + r;
                float v = acc[mi][ni][r] + bv[ni];
                if (which)
                    omf[i * OMP_ + jj] = v;
                else
                    valueb[i * C_ + jj] = f2h(v);   // FP16 value (fma_mix gather)
            }
        }
    }
}

// ---------------------------------------------------------------------------
// Fused sampling + output projection: EXACT R6 configuration (verified twice:
// R6 44.2 us, R8 44.1-44.9 us; WRITE = logical 32.8 MB, FETCH 23.1 MB).
// 256 thr / 4 waves, barrier-free wave-local rep loop, om staged via
// global_load_lds, fp16 value + fma_mix gather, XCD-pinned grid (N, L/64),
// 112 VGPR, LDS 57.4 KB, LB(256,2).
// ---------------------------------------------------------------------------
__global__ __launch_bounds__(256, 2) void samplegemm_kernel(const unsigned short* __restrict__ value,
                                                            const float* __restrict__ om,
                                                            const unsigned short* __restrict__ opw,
                                                            float* __restrict__ out) {
    const int n = blockIdx.x, l0 = blockIdx.y * 64;
    const int tid = threadIdx.x;
    __shared__ __align__(16) unsigned short interm[64 * 256];   // 32 KB, swizzled
    __shared__ __align__(16) float ombuf[8][224];               // 7 KB om-row stage
    __shared__ float4 wgt[64][9];                               // 9.2 KB
    __shared__ uint4  soff[64][9];                              // 9.2 KB

    const int wave = tid >> 6, lane = tid & 63;
    const int lp = tid >> 2;            // pair 0..63; wave w owns lp 16w..16w+15
    const int g = lp & 7;
    const int c8i = tid & 3;
    const int slot = tid & 31;          // = g*4 + c8i
    const char* vbase = (const char*)(value + (size_t)n * L_ * C_);
    const char* vb = vbase + (size_t)(g * CG_ + c8i * 8) * 2;

    const float* omn = om + (size_t)n * L_ * OMP_;
    float* obase = &ombuf[2 * wave][0];                 // wave-uniform dest base

    const int s0row = (lane < 56) ? 0 : 1;              // 0 -> p0, 1 -> p1
    const int s0idx = (lane < 56) ? lane : (lane - 56);

#define STAGE_OM(REP) { \
        const float* r0_ = omn + (size_t)(l0 + (REP) * 8 + 2 * wave) * OMP_; \
        gld16(r0_ + (size_t)s0row * OMP_ + s0idx * 4, obase); \
        if (lane < 48) gld16(r0_ + OMP_ + (8 + lane) * 4, (char*)obase + 1024); }

    STAGE_OM(0)

    for (int rep = 0; rep < 8; rep++) {
        // gld16 -> LDS dependency is untracked by the compiler: explicit drain.
        asm volatile("s_waitcnt vmcnt(0)" ::: "memory");
        // --- tap compute: 144 items (16 pairs x 9 taps) over 64 lanes ---
#pragma unroll
        for (int j = 0; j < 3; j++) {
            if (!(j == 2 && lane >= 16)) {
                int it = lane + j * 64;                  // 0..143
                int pl_loc = it / 9, k = it - pl_loc * 9;
                int pl = wave * 16 + pl_loc;
                int pic = pl >> 3;                       // pixel-in-chunk 0..7
                const float* ob2 = &ombuf[pic][(pl & 7) * 27];
                float offy = ob2[2 * k], offx = ob2[2 * k + 1], mk = ob2[18 + k];
                float4 wq; uint4 sq;
                tapcalc(l0 + rep * 8 + pic, k, offy, offx, mk, wq, sq);
                wgt[pl][k] = wq; soff[pl][k] = sq;
            }
        }
        // order: ombuf ds_reads above stay before the overwriting stage below
        asm volatile("" ::: "memory");
        if (rep < 7) STAGE_OM(rep + 1)
        asm volatile("" ::: "memory");
        // --- gather (table ds_writes -> ds_reads are same-wave, in-order) ---
        const int p = rep * 8 + (lp >> 3);
        float acc[8] = {0.f, 0.f, 0.f, 0.f, 0.f, 0.f, 0.f, 0.f};
#pragma unroll
        for (int k = 0; k < K_; k++) {
            float4 wk = wgt[lp][k];
            uint4  ok = soff[lp][k];
            const uint4 v00 = *(const uint4*)(vb + ok.x);
            const uint4 v01 = *(const uint4*)(vb + ok.y);
            const uint4 v10 = *(const uint4*)(vb + ok.z);
            const uint4 v11 = *(const uint4*)(vb + ok.w);
            // fp16 value: 1 VALU/elem via v_fma_mix_f32 (fpext fused into fma)
#define ACC8(V, WW) { \
            const __half2* h_ = (const __half2*)&V; \
            acc[0] += WW * __half2float(h_[0].x); acc[1] += WW * __half2float(h_[0].y); \
            acc[2] += WW * __half2float(h_[1].x); acc[3] += WW * __half2float(h_[1].y); \
            acc[4] += WW * __half2float(h_[2].x); acc[5] += WW * __half2float(h_[2].y); \
            acc[6] += WW * __half2float(h_[3].x); acc[7] += WW * __half2float(h_[3].y); }
            ACC8(v00, wk.x) ACC8(v01, wk.y) ACC8(v10, wk.z) ACC8(v11, wk.w)
#undef ACC8
        }
        uint4 pk;
        unsigned short* ps = (unsigned short*)&pk;
#pragma unroll
        for (int i = 0; i < 8; i++) ps[i] = f2bf(acc[i]);
        int phys = slot ^ (p & 7);
        *(uint4*)&interm[p * 256 + phys * 8] = pk;      // wave-private rows
    }
#undef STAGE_OM
    __syncthreads();   // the ONLY block barrier: interm ready for phase C

    // --- Phase C: per wave 64q x 64px, 4x4 frags, K=256 in 8 steps ---
    const int lm = lane & 15, kq = lane >> 4;
    const int q0w = wave * 64;
    frag_cd acc2[4][4];
#pragma unroll
    for (int a = 0; a < 4; a++)
#pragma unroll
        for (int c = 0; c < 4; c++) acc2[a][c] = (frag_cd){0.f, 0.f, 0.f, 0.f};

    for (int k0 = 0; k0 < C_; k0 += 32) {
        frag_ab af[4], bfr[4];
#pragma unroll
        for (int mi = 0; mi < 4; mi++)
            af[mi] = *(const frag_ab*)(opw + (size_t)(q0w + mi * 16 + lm) * C_ + k0 + kq * 8);
#pragma unroll
        for (int ni = 0; ni < 4; ni++) {
            int pxr = ni * 16 + lm;
            int phys = (k0 / 8 + kq) ^ (pxr & 7);
            bfr[ni] = *(const frag_ab*)&interm[pxr * 256 + phys * 8];
        }
#pragma unroll
        for (int mi = 0; mi < 4; mi++)
#pragma unroll
            for (int ni = 0; ni < 4; ni++)
                acc2[mi][ni] = __builtin_amdgcn_mfma_f32_16x16x32_bf16(af[mi], bfr[ni], acc2[mi][ni], 0, 0, 0);
    }

    float* ob = out + (size_t)n * C_ * L_ + l0;
#pragma unroll
    for (int mi = 0; mi < 4; mi++) {
#pragma unroll
        for (int ni = 0; ni < 4; ni++) {
            int pxr = ni * 16 + lm;
#pragma unroll
            for (int r = 0; r < 4; r++) {
                int q = q0w + mi * 16 + kq * 4 + r;
                ob[(size_t)q * L_ + pxr] = acc2[mi][ni][r];
            }
        }
    }
}

// ---------------------------------------------------------------------------
// Workspace layout (84,280,320 B total):
//   [0,        16777216)  xb  [n][kb][l][32] bf16 (channel-tiled)
//   [16777216, 33554432)  omb [n][kb][l][32] bf16 (channel-tiled)
//   [33554432, 50331648)  valueb (n,L,C) FP16
//   [50331648, 83886080)  omf (n,L,256) fp32 (full rows, pad cols zero)
//   [83886080, ...)       vp_wb, om_wb, op_wb bf16 (128KB each), om_bp fp32
// ---------------------------------------------------------------------------
extern "C" void kernel_launch(void* const* d_in, const int* in_sizes, int n_in,
                              void* d_out, int out_size, void* d_ws, size_t ws_size,
                              hipStream_t stream) {
    const float* x    = (const float*)d_in[0];
    const float* dw_w = (const float*)d_in[1];
    const float* dw_b = (const float*)d_in[2];
    const float* om_w = (const float*)d_in[3];
    const float* om_b = (const float*)d_in[4];
    const float* vp_w = (const float*)d_in[5];
    const float* vp_b = (const float*)d_in[6];
    const float* op_w = (const float*)d_in[7];
    float* out = (float*)d_out;

    char* ws = (char*)d_ws;
    unsigned short* xb      = (unsigned short*)(ws);
    unsigned short* omb     = (unsigned short*)(ws + 16777216);
    unsigned short* valueb  = (unsigned short*)(ws + 33554432);
    float*          omf     = (float*)(ws + 50331648);
    unsigned short* vp_wb   = (unsigned short*)(ws + 83886080);
    unsigned short* om_wb   = (unsigned short*)(ws + 84017152);
    unsigned short* op_wb   = (unsigned short*)(ws + 84148224);
    float*          om_bp   = (float*)(ws + 84279296);

    // 1) fused depthwise conv + x transpose + weight conversion (4 rows/block)
    prep_kernel<<<dim3(C_ / 32, H_ / 4, N_), 256, 0, stream>>>(
        x, dw_w, dw_b, vp_w, om_w, om_b, op_w,
        xb, omb, vp_wb, om_wb, om_bp, op_wb);
    // 2) value = xb @ vp_w^T + vp_b (fp16)  AND  om = omb @ om_w^T + om_b
    //    A-direct + double-buffered B-only staging (8 barriers)
    gemm12_kernel<<<dim3(256, 1, 2), 256, 0, stream>>>(
        xb, omb, vp_wb, om_wb, vp_b, om_bp, valueb, omf);
    // 3) fused sampling + output projection -> out (NCHW fp32)
    //    grid (N, L/64): wgid%8 == n pins each batch's value slice to one XCD L2
    samplegemm_kernel<<<dim3(N_, L_ / 64), 256, 0, stream>>>(valueb, omf, op_wb, out);
}

// Round 11
// 162.464 us; speedup vs baseline: 2.4927x; 1.0142x over previous
//
#include <hip/hip_runtime.h>
#include <hip/hip_fp16.h>
#include <math.h>

// Problem constants
#define N_  8
#define C_  256
#define G_  8
#define CG_ 32
#define K_  9
#define H_  64
#define W_  64
#define L_  (H_*W_)      // 4096
#define OM_ 216          // G*K*3
#define OMP_ 256         // padded om row stride (fp32), groups packed at g*27

using frag_ab = __attribute__((ext_vector_type(8))) short;   // 8 bf16
using frag_cd = __attribute__((ext_vector_type(4))) float;   // 4 fp32

__device__ __forceinline__ unsigned short f2bf(float f) {    // RNE fp32->bf16
    unsigned int u = __float_as_uint(f);
    u += 0x7FFFu + ((u >> 16) & 1u);
    return (unsigned short)(u >> 16);
}
__device__ __forceinline__ unsigned short f2h(float f) {     // RNE fp32->fp16
    return __half_as_ushort(__float2half(f));
}

__device__ __forceinline__ void gld16(const void* g, void* l) {
    __builtin_amdgcn_global_load_lds((const __attribute__((address_space(1))) void*)g,
                                     (__attribute__((address_space(3))) void*)l, 16, 0, 0);
}

// bilinear tap -> (4 weights, 4 row-offsets<<9)
__device__ __forceinline__ void tapcalc(int l, int k, float offy, float offx, float mk,
                                        float4& wq, uint4& sq) {
    const int y = l >> 6, xp = l & 63;
    float py = (float)(y + k / 3 - 1) + offy;
    float px = (float)(xp + k % 3 - 1) + offx;
    float fy = floorf(py), fx = floorf(px);
    float ty = py - fy, tx = px - fx;
    int y0 = (int)fy, x0i = (int)fx;
    int y1 = y0 + 1, x1 = x0i + 1;
    float vy0 = ((unsigned)y0 < (unsigned)H_) ? 1.f : 0.f;
    float vy1 = ((unsigned)y1 < (unsigned)H_) ? 1.f : 0.f;
    float vx0 = ((unsigned)x0i < (unsigned)W_) ? 1.f : 0.f;
    float vx1 = ((unsigned)x1 < (unsigned)W_) ? 1.f : 0.f;
    int cy0 = min(max(y0, 0), H_ - 1), cy1 = min(max(y1, 0), H_ - 1);
    int cx0 = min(max(x0i, 0), W_ - 1), cx1 = min(max(x1, 0), W_ - 1);
    wq = make_float4(mk * (1.f - ty) * (1.f - tx) * vy0 * vx0,
                     mk * (1.f - ty) * tx         * vy0 * vx1,
                     mk * ty         * (1.f - tx) * vy1 * vx0,
                     mk * ty         * tx         * vy1 * vx1);
    sq = make_uint4((unsigned)((cy0 * W_ + cx0) << 9),
                    (unsigned)((cy0 * W_ + cx1) << 9),
                    (unsigned)((cy1 * W_ + cx0) << 9),
                    (unsigned)((cy1 * W_ + cx1) << 9));
}

// ---------------------------------------------------------------------------
// Fused prep, R11 = exact R2 revert (proven fastest prep: rest-budget 119.1
// vs 126.0 for the R4 4-row variant; R2->R4 changed only prep, so the +7 us
// is attributable). Single output row per block: xs[3][32][66]+os = 35.5 KB
// LDS -> 4 blocks/CU, grid (8,64,8) = 4096 blocks -> 16 waves/CU. prep is
// occupancy/latency-bound, NOT bytes-bound: the 4-row halo "optimization"
// halved occupancy to save traffic and lost 7 us (same lesson as R4's
// bytes-law refutation on samplegemm).
// grid (C/32, H, N), block 256.
// ---------------------------------------------------------------------------
__global__ __launch_bounds__(256) void prep_kernel(const float* __restrict__ x,
                                                   const float* __restrict__ w,
                                                   const float* __restrict__ b,
                                                   const float* __restrict__ vp_w,
                                                   const float* __restrict__ om_w,
                                                   const float* __restrict__ om_b,
                                                   const float* __restrict__ op_w,
                                                   unsigned short* __restrict__ xb,
                                                   unsigned short* __restrict__ omb,
                                                   unsigned short* __restrict__ vp_wb,
                                                   unsigned short* __restrict__ om_wb,
                                                   float* __restrict__ om_bp,
                                                   unsigned short* __restrict__ op_wb) {
    const int n = blockIdx.z, y = blockIdx.y, c0 = blockIdx.x * 32;
    const int tid = threadIdx.x;
    __shared__ float xs[3][32][66];
    __shared__ __align__(16) unsigned short os[2][64][40];  // [0]=x bf16, [1]=conv
    if (tid < 192) {    // zero the x = -1 / 64 halo columns
        int r = tid / 64, c = (tid / 2) % 32, e = tid & 1;
        xs[r][c][e * 65] = 0.f;
    }
    const float* xbase = x + ((size_t)n * C_ + c0) * L_;
    for (int i = tid; i < 3 * 32 * 16; i += 256) {   // 3 rows x 32 ch x 16 float4
        int r = i >> 9, rem = i & 511, c = rem >> 4, x4 = (rem & 15) * 4;
        int yy = y + r - 1;
        float4 v = make_float4(0.f, 0.f, 0.f, 0.f);
        if ((unsigned)yy < (unsigned)H_) v = *(const float4*)(xbase + (size_t)c * L_ + yy * W_ + x4);
        xs[r][c][1 + x4] = v.x; xs[r][c][2 + x4] = v.y;
        xs[r][c][3 + x4] = v.z; xs[r][c][4 + x4] = v.w;
    }
    __syncthreads();

    const int c = tid & 31, x0 = (tid >> 5) * 8;
    float wv[9];
#pragma unroll
    for (int i = 0; i < 9; i++) wv[i] = w[(c0 + c) * 9 + i];
    const float bias = b[c0 + c];
    float o[8];
#pragma unroll
    for (int j = 0; j < 8; j++) o[j] = bias;
#pragma unroll
    for (int r = 0; r < 3; r++) {
        float v[10];
#pragma unroll
        for (int d = 0; d < 10; d++) v[d] = xs[r][c][x0 + d];
#pragma unroll
        for (int j = 0; j < 8; j++)
            o[j] += wv[r * 3] * v[j] + wv[r * 3 + 1] * v[j + 1] + wv[r * 3 + 2] * v[j + 2];
    }
#pragma unroll
    for (int j = 0; j < 8; j++) {
        os[0][x0 + j][c] = f2bf(xs[1][c][1 + x0 + j]);
        os[1][x0 + j][c] = f2bf(o[j]);
    }
    __syncthreads();

    const int l = tid >> 2, c8 = (tid & 3) * 8;
    uint4 va = *(const uint4*)&os[0][l][c8];
    uint4 vc = *(const uint4*)&os[1][l][c8];
    // channel-tiled: [n][kb][l][32]; wave store = contiguous 1 KB
    size_t dst = (((size_t)n * 8 + blockIdx.x) * L_ + y * W_ + l) * 32 + c8;
    *(uint4*)(xb + dst) = va;
    *(uint4*)(omb + dst) = vc;

    // Weight conversion, folded in: blocks with n==0 cover all indices.
    if (n == 0) {
        int idx = (blockIdx.x + 8 * blockIdx.y) * 256 + tid;   // 0..131071
        if (idx < C_ * C_) {
            vp_wb[idx] = f2bf(vp_w[idx]);
            op_wb[idx] = f2bf(op_w[idx]);
            om_wb[idx] = (idx < OM_ * C_) ? f2bf(om_w[idx]) : (unsigned short)0;
        }
        if (idx < OMP_) om_bp[idx] = (idx < OM_) ? om_b[idx] : 0.f;
    }
}

// ---------------------------------------------------------------------------
// Merged GEMM1+GEMM2, R10-proven: A-DIRECT + double-buffered B-only staging.
// (R10: total 166.8 -> 164.8 with this kernel; keep.)
// grid (256,1,2), block 256 (4 waves), LB(256,2), LDS 32 KB.
// ---------------------------------------------------------------------------
__global__ __launch_bounds__(256, 2) void gemm12_kernel(const unsigned short* __restrict__ xb,
                                                        const unsigned short* __restrict__ omb,
                                                        const unsigned short* __restrict__ vp_wb,
                                                        const unsigned short* __restrict__ om_wb,
                                                        const float* __restrict__ vp_b,
                                                        const float* __restrict__ om_bp,
                                                        unsigned short* __restrict__ valueb,
                                                        float* __restrict__ omf) {
    __shared__ unsigned short Bs[2][256 * 32];   // 32 KB double-buffered B
    const int which = blockIdx.z;
    const unsigned short* A = which ? omb : xb;
    const unsigned short* B = which ? om_wb : vp_wb;
    const float* bias = which ? om_bp : vp_b;
    const int tid = threadIdx.x;
    const long i0 = (long)blockIdx.x * 128;
    const int nA = (int)(i0 >> 12);          // batch index (128-row blocks never straddle n)
    const int lofs = (int)(i0 & 4095);
    const int wave = tid >> 6, lane = tid & 63;
    const int iw = (wave & 1) * 64, jw = (wave >> 1) * 128;
    const int lm = lane & 15, kq = lane >> 4;
    const int srow = tid >> 2, scol = (tid & 3) * 8;

    frag_cd acc[4][8];
#pragma unroll
    for (int a = 0; a < 4; a++)
#pragma unroll
        for (int c = 0; c < 8; c++) acc[a][c] = (frag_cd){0.f, 0.f, 0.f, 0.f};

    // A-direct lane base (R8-verified): frag = 1 KB contiguous per wave
    const unsigned short* Abase = A + (((size_t)nA * 8) * L_ + lofs + iw + lm) * 32 + kq * 8;
    // B staging source (R6-verified): per-lane row srow, cols scol..scol+7
    const unsigned short* gb0 = B + (long)srow * C_ + scol;

#define STAGE_B(KS, BUF) { \
        const unsigned short* gb_ = gb0 + (KS) * 32; \
        gld16(gb_,             Bs[BUF] + tid * 8); \
        gld16(gb_ + 64 * C_,   Bs[BUF] + 2048 + tid * 8); \
        gld16(gb_ + 128 * C_,  Bs[BUF] + 4096 + tid * 8); \
        gld16(gb_ + 192 * C_,  Bs[BUF] + 6144 + tid * 8); }

    STAGE_B(0, 0)

#pragma unroll
    for (int ks = 0; ks < 8; ks++) {     // k0 = ks*32
        const int buf = ks & 1;
        // drain my wave's gld16 into Bs[buf], then publish across waves
        asm volatile("s_waitcnt vmcnt(0)" ::: "memory");
        __syncthreads();
        if (ks < 7) STAGE_B(ks + 1, buf ^ 1)   // overlaps with MFMA below
        frag_ab af[4], bfr[8];
#pragma unroll
        for (int mi = 0; mi < 4; mi++)
            af[mi] = *(const frag_ab*)(Abase + ((size_t)ks * L_ + mi * 16) * 32);
#pragma unroll
        for (int ni = 0; ni < 8; ni++)
            bfr[ni] = *(const frag_ab*)&Bs[buf][(jw + ni * 16 + lm) * 32 + kq * 8];
#pragma unroll
        for (int mi = 0; mi < 4; mi++)
#pragma unroll
            for (int ni = 0; ni < 8; ni++)
                acc[mi][ni] = __builtin_amdgcn_mfma_f32_16x16x32_bf16(af[mi], bfr[ni], acc[mi][ni], 0, 0, 0);
    }
#undef STAGE_B

    float bv[8];
#pragma unroll
    for (int ni = 0; ni < 8; ni++)
        bv[ni] = bias[jw + ni * 16 + lm];

    const long ibase = i0 + iw + kq * 4;
    const int jbase = jw + lm;
#pragma unroll
    for (int mi = 0; mi < 4; mi++) {
#pragma unroll
        for (int ni = 0; ni < 8; ni++) {
            int jj = jbase + ni * 16;
#pragma unroll
            for (int r = 0; r < 4; r++) {
                long i = ibase + mi * 16 + r;
                float v = acc[mi][ni][r] + bv[ni];
                if (which)
                    omf[i * OMP_ + jj] = v;
                else
                    valueb[i * C_ + jj] = f2h(v);   // FP16 value (fma_mix gather)
            }
        }
    }
}

// ---------------------------------------------------------------------------
// Fused sampling + output projection: EXACT R6 configuration (verified 3x:
// R6 44.2, R8 44.1-44.9, R10 43.9-46.0 us; WRITE = logical 32.8 MB,
// FETCH 23.1 MB). 256 thr / 4 waves, barrier-free wave-local rep loop, om
// staged via global_load_lds, fp16 value + fma_mix gather, XCD-pinned grid
// (N, L/64), 112 VGPR, LDS 57.4 KB, LB(256,2).
// ---------------------------------------------------------------------------
__global__ __launch_bounds__(256, 2) void samplegemm_kernel(const unsigned short* __restrict__ value,
                                                            const float* __restrict__ om,
                                                            const unsigned short* __restrict__ opw,
                                                            float* __restrict__ out) {
    const int n = blockIdx.x, l0 = blockIdx.y * 64;
    const int tid = threadIdx.x;
    __shared__ __align__(16) unsigned short interm[64 * 256];   // 32 KB, swizzled
    __shared__ __align__(16) float ombuf[8][224];               // 7 KB om-row stage
    __shared__ float4 wgt[64][9];                               // 9.2 KB
    __shared__ uint4  soff[64][9];                              // 9.2 KB

    const int wave = tid >> 6, lane = tid & 63;
    const int lp = tid >> 2;            // pair 0..63; wave w owns lp 16w..16w+15
    const int g = lp & 7;
    const int c8i = tid & 3;
    const int slot = tid & 31;          // = g*4 + c8i
    const char* vbase = (const char*)(value + (size_t)n * L_ * C_);
    const char* vb = vbase + (size_t)(g * CG_ + c8i * 8) * 2;

    const float* omn = om + (size_t)n * L_ * OMP_;
    float* obase = &ombuf[2 * wave][0];                 // wave-uniform dest base

    const int s0row = (lane < 56) ? 0 : 1;              // 0 -> p0, 1 -> p1
    const int s0idx = (lane < 56) ? lane : (lane - 56);

#define STAGE_OM(REP) { \
        const float* r0_ = omn + (size_t)(l0 + (REP) * 8 + 2 * wave) * OMP_; \
        gld16(r0_ + (size_t)s0row * OMP_ + s0idx * 4, obase); \
        if (lane < 48) gld16(r0_ + OMP_ + (8 + lane) * 4, (char*)obase + 1024); }

    STAGE_OM(0)

    for (int rep = 0; rep < 8; rep++) {
        // gld16 -> LDS dependency is untracked by the compiler: explicit drain.
        asm volatile("s_waitcnt vmcnt(0)" ::: "memory");
        // --- tap compute: 144 items (16 pairs x 9 taps) over 64 lanes ---
#pragma unroll
        for (int j = 0; j < 3; j++) {
            if (!(j == 2 && lane >= 16)) {
                int it = lane + j * 64;                  // 0..143
                int pl_loc = it / 9, k = it - pl_loc * 9;
                int pl = wave * 16 + pl_loc;
                int pic = pl >> 3;                       // pixel-in-chunk 0..7
                const float* ob2 = &ombuf[pic][(pl & 7) * 27];
                float offy = ob2[2 * k], offx = ob2[2 * k + 1], mk = ob2[18 + k];
                float4 wq; uint4 sq;
                tapcalc(l0 + rep * 8 + pic, k, offy, offx, mk, wq, sq);
                wgt[pl][k] = wq; soff[pl][k] = sq;
            }
        }
        // order: ombuf ds_reads above stay before the overwriting stage below
        asm volatile("" ::: "memory");
        if (rep < 7) STAGE_OM(rep + 1)
        asm volatile("" ::: "memory");
        // --- gather (table ds_writes -> ds_reads are same-wave, in-order) ---
        const int p = rep * 8 + (lp >> 3);
        float acc[8] = {0.f, 0.f, 0.f, 0.f, 0.f, 0.f, 0.f, 0.f};
#pragma unroll
        for (int k = 0; k < K_; k++) {
            float4 wk = wgt[lp][k];
            uint4  ok = soff[lp][k];
            const uint4 v00 = *(const uint4*)(vb + ok.x);
            const uint4 v01 = *(const uint4*)(vb + ok.y);
            const uint4 v10 = *(const uint4*)(vb + ok.z);
            const uint4 v11 = *(const uint4*)(vb + ok.w);
            // fp16 value: 1 VALU/elem via v_fma_mix_f32 (fpext fused into fma)
#define ACC8(V, WW) { \
            const __half2* h_ = (const __half2*)&V; \
            acc[0] += WW * __half2float(h_[0].x); acc[1] += WW * __half2float(h_[0].y); \
            acc[2] += WW * __half2float(h_[1].x); acc[3] += WW * __half2float(h_[1].y); \
            acc[4] += WW * __half2float(h_[2].x); acc[5] += WW * __half2float(h_[2].y); \
            acc[6] += WW * __half2float(h_[3].x); acc[7] += WW * __half2float(h_[3].y); }
            ACC8(v00, wk.x) ACC8(v01, wk.y) ACC8(v10, wk.z) ACC8(v11, wk.w)
#undef ACC8
        }
        uint4 pk;
        unsigned short* ps = (unsigned short*)&pk;
#pragma unroll
        for (int i = 0; i < 8; i++) ps[i] = f2bf(acc[i]);
        int phys = slot ^ (p & 7);
        *(uint4*)&interm[p * 256 + phys * 8] = pk;      // wave-private rows
    }
#undef STAGE_OM
    __syncthreads();   // the ONLY block barrier: interm ready for phase C

    // --- Phase C: per wave 64q x 64px, 4x4 frags, K=256 in 8 steps ---
    const int lm = lane & 15, kq = lane >> 4;
    const int q0w = wave * 64;
    frag_cd acc2[4][4];
#pragma unroll
    for (int a = 0; a < 4; a++)
#pragma unroll
        for (int c = 0; c < 4; c++) acc2[a][c] = (frag_cd){0.f, 0.f, 0.f, 0.f};

    for (int k0 = 0; k0 < C_; k0 += 32) {
        frag_ab af[4], bfr[4];
#pragma unroll
        for (int mi = 0; mi < 4; mi++)
            af[mi] = *(const frag_ab*)(opw + (size_t)(q0w + mi * 16 + lm) * C_ + k0 + kq * 8);
#pragma unroll
        for (int ni = 0; ni < 4; ni++) {
            int pxr = ni * 16 + lm;
            int phys = (k0 / 8 + kq) ^ (pxr & 7);
            bfr[ni] = *(const frag_ab*)&interm[pxr * 256 + phys * 8];
        }
#pragma unroll
        for (int mi = 0; mi < 4; mi++)
#pragma unroll
            for (int ni = 0; ni < 4; ni++)
                acc2[mi][ni] = __builtin_amdgcn_mfma_f32_16x16x32_bf16(af[mi], bfr[ni], acc2[mi][ni], 0, 0, 0);
    }

    float* ob = out + (size_t)n * C_ * L_ + l0;
#pragma unroll
    for (int mi = 0; mi < 4; mi++) {
#pragma unroll
        for (int ni = 0; ni < 4; ni++) {
            int pxr = ni * 16 + lm;
#pragma unroll
            for (int r = 0; r < 4; r++) {
                int q = q0w + mi * 16 + kq * 4 + r;
                ob[(size_t)q * L_ + pxr] = acc2[mi][ni][r];
            }
        }
    }
}

// ---------------------------------------------------------------------------
// Workspace layout (84,280,320 B total):
//   [0,        16777216)  xb  [n][kb][l][32] bf16 (channel-tiled)
//   [16777216, 33554432)  omb [n][kb][l][32] bf16 (channel-tiled)
//   [33554432, 50331648)  valueb (n,L,C) FP16
//   [50331648, 83886080)  omf (n,L,256) fp32 (full rows, pad cols zero)
//   [83886080, ...)       vp_wb, om_wb, op_wb bf16 (128KB each), om_bp fp32
// ---------------------------------------------------------------------------
extern "C" void kernel_launch(void* const* d_in, const int* in_sizes, int n_in,
                              void* d_out, int out_size, void* d_ws, size_t ws_size,
                              hipStream_t stream) {
    const float* x    = (const float*)d_in[0];
    const float* dw_w = (const float*)d_in[1];
    const float* dw_b = (const float*)d_in[2];
    const float* om_w = (const float*)d_in[3];
    const float* om_b = (const float*)d_in[4];
    const float* vp_w = (const float*)d_in[5];
    const float* vp_b = (const float*)d_in[6];
    const float* op_w = (const float*)d_in[7];
    float* out = (float*)d_out;

    char* ws = (char*)d_ws;
    unsigned short* xb      = (unsigned short*)(ws);
    unsigned short* omb     = (unsigned short*)(ws + 16777216);
    unsigned short* valueb  = (unsigned short*)(ws + 33554432);
    float*          omf     = (float*)(ws + 50331648);
    unsigned short* vp_wb   = (unsigned short*)(ws + 83886080);
    unsigned short* om_wb   = (unsigned short*)(ws + 84017152);
    unsigned short* op_wb   = (unsigned short*)(ws + 84148224);
    float*          om_bp   = (float*)(ws + 84279296);

    // 1) fused depthwise conv + x transpose + weight conversion (1 row/block,
    //    4 blocks/CU — R2-proven fastest prep)
    prep_kernel<<<dim3(C_ / 32, H_, N_), 256, 0, stream>>>(
        x, dw_w, dw_b, vp_w, om_w, om_b, op_w,
        xb, omb, vp_wb, om_wb, om_bp, op_wb);
    // 2) value = xb @ vp_w^T + vp_b (fp16)  AND  om = omb @ om_w^T + om_b
    //    A-direct + double-buffered B-only staging (R10-proven)
    gemm12_kernel<<<dim3(256, 1, 2), 256, 0, stream>>>(
        xb, omb, vp_wb, om_wb, vp_b, om_bp, valueb, omf);
    // 3) fused sampling + output projection -> out (NCHW fp32)
    //    grid (N, L/64): wgid%8 == n pins each batch's value slice to one XCD L2
    samplegemm_kernel<<<dim3(N_, L_ / 64), 256, 0, stream>>>(valueb, omf, op_wb, out);
}

// Round 12
// 160.026 us; speedup vs baseline: 2.5307x; 1.0152x over previous
//
#include <hip/hip_runtime.h>
#include <hip/hip_fp16.h>
#include <math.h>

// Problem constants
#define N_  8
#define C_  256
#define G_  8
#define CG_ 32
#define K_  9
#define H_  64
#define W_  64
#define L_  (H_*W_)      // 4096
#define OM_ 216          // G*K*3
#define OMP_ 256         // padded om row stride (now fp16), groups packed g*27

using frag_ab = __attribute__((ext_vector_type(8))) short;   // 8 bf16
using frag_cd = __attribute__((ext_vector_type(4))) float;   // 4 fp32

__device__ __forceinline__ unsigned short f2bf(float f) {    // RNE fp32->bf16
    unsigned int u = __float_as_uint(f);
    u += 0x7FFFu + ((u >> 16) & 1u);
    return (unsigned short)(u >> 16);
}
__device__ __forceinline__ unsigned short f2h(float f) {     // RNE fp32->fp16
    return __half_as_ushort(__float2half(f));
}

__device__ __forceinline__ void gld16(const void* g, void* l) {
    __builtin_amdgcn_global_load_lds((const __attribute__((address_space(1))) void*)g,
                                     (__attribute__((address_space(3))) void*)l, 16, 0, 0);
}

// bilinear tap -> (4 weights, 4 row-offsets<<9)
__device__ __forceinline__ void tapcalc(int l, int k, float offy, float offx, float mk,
                                        float4& wq, uint4& sq) {
    const int y = l >> 6, xp = l & 63;
    float py = (float)(y + k / 3 - 1) + offy;
    float px = (float)(xp + k % 3 - 1) + offx;
    float fy = floorf(py), fx = floorf(px);
    float ty = py - fy, tx = px - fx;
    int y0 = (int)fy, x0i = (int)fx;
    int y1 = y0 + 1, x1 = x0i + 1;
    float vy0 = ((unsigned)y0 < (unsigned)H_) ? 1.f : 0.f;
    float vy1 = ((unsigned)y1 < (unsigned)H_) ? 1.f : 0.f;
    float vx0 = ((unsigned)x0i < (unsigned)W_) ? 1.f : 0.f;
    float vx1 = ((unsigned)x1 < (unsigned)W_) ? 1.f : 0.f;
    int cy0 = min(max(y0, 0), H_ - 1), cy1 = min(max(y1, 0), H_ - 1);
    int cx0 = min(max(x0i, 0), W_ - 1), cx1 = min(max(x1, 0), W_ - 1);
    wq = make_float4(mk * (1.f - ty) * (1.f - tx) * vy0 * vx0,
                     mk * (1.f - ty) * tx         * vy0 * vx1,
                     mk * ty         * (1.f - tx) * vy1 * vx0,
                     mk * ty         * tx         * vy1 * vx1);
    sq = make_uint4((unsigned)((cy0 * W_ + cx0) << 9),
                    (unsigned)((cy0 * W_ + cx1) << 9),
                    (unsigned)((cy1 * W_ + cx0) << 9),
                    (unsigned)((cy1 * W_ + cx1) << 9));
}

// ---------------------------------------------------------------------------
// Fused prep: exact R2/R11 (proven fastest: 1 row/block, 35.5 KB LDS,
// 4 blocks/CU, 16 waves/CU). grid (C/32, H, N), block 256.
// ---------------------------------------------------------------------------
__global__ __launch_bounds__(256) void prep_kernel(const float* __restrict__ x,
                                                   const float* __restrict__ w,
                                                   const float* __restrict__ b,
                                                   const float* __restrict__ vp_w,
                                                   const float* __restrict__ om_w,
                                                   const float* __restrict__ om_b,
                                                   const float* __restrict__ op_w,
                                                   unsigned short* __restrict__ xb,
                                                   unsigned short* __restrict__ omb,
                                                   unsigned short* __restrict__ vp_wb,
                                                   unsigned short* __restrict__ om_wb,
                                                   float* __restrict__ om_bp,
                                                   unsigned short* __restrict__ op_wb) {
    const int n = blockIdx.z, y = blockIdx.y, c0 = blockIdx.x * 32;
    const int tid = threadIdx.x;
    __shared__ float xs[3][32][66];
    __shared__ __align__(16) unsigned short os[2][64][40];  // [0]=x bf16, [1]=conv
    if (tid < 192) {    // zero the x = -1 / 64 halo columns
        int r = tid / 64, c = (tid / 2) % 32, e = tid & 1;
        xs[r][c][e * 65] = 0.f;
    }
    const float* xbase = x + ((size_t)n * C_ + c0) * L_;
    for (int i = tid; i < 3 * 32 * 16; i += 256) {   // 3 rows x 32 ch x 16 float4
        int r = i >> 9, rem = i & 511, c = rem >> 4, x4 = (rem & 15) * 4;
        int yy = y + r - 1;
        float4 v = make_float4(0.f, 0.f, 0.f, 0.f);
        if ((unsigned)yy < (unsigned)H_) v = *(const float4*)(xbase + (size_t)c * L_ + yy * W_ + x4);
        xs[r][c][1 + x4] = v.x; xs[r][c][2 + x4] = v.y;
        xs[r][c][3 + x4] = v.z; xs[r][c][4 + x4] = v.w;
    }
    __syncthreads();

    const int c = tid & 31, x0 = (tid >> 5) * 8;
    float wv[9];
#pragma unroll
    for (int i = 0; i < 9; i++) wv[i] = w[(c0 + c) * 9 + i];
    const float bias = b[c0 + c];
    float o[8];
#pragma unroll
    for (int j = 0; j < 8; j++) o[j] = bias;
#pragma unroll
    for (int r = 0; r < 3; r++) {
        float v[10];
#pragma unroll
        for (int d = 0; d < 10; d++) v[d] = xs[r][c][x0 + d];
#pragma unroll
        for (int j = 0; j < 8; j++)
            o[j] += wv[r * 3] * v[j] + wv[r * 3 + 1] * v[j + 1] + wv[r * 3 + 2] * v[j + 2];
    }
#pragma unroll
    for (int j = 0; j < 8; j++) {
        os[0][x0 + j][c] = f2bf(xs[1][c][1 + x0 + j]);
        os[1][x0 + j][c] = f2bf(o[j]);
    }
    __syncthreads();

    const int l = tid >> 2, c8 = (tid & 3) * 8;
    uint4 va = *(const uint4*)&os[0][l][c8];
    uint4 vc = *(const uint4*)&os[1][l][c8];
    // channel-tiled: [n][kb][l][32]; wave store = contiguous 1 KB
    size_t dst = (((size_t)n * 8 + blockIdx.x) * L_ + y * W_ + l) * 32 + c8;
    *(uint4*)(xb + dst) = va;
    *(uint4*)(omb + dst) = vc;

    // Weight conversion, folded in: blocks with n==0 cover all indices.
    if (n == 0) {
        int idx = (blockIdx.x + 8 * blockIdx.y) * 256 + tid;   // 0..131071
        if (idx < C_ * C_) {
            vp_wb[idx] = f2bf(vp_w[idx]);
            op_wb[idx] = f2bf(op_w[idx]);
            om_wb[idx] = (idx < OM_ * C_) ? f2bf(om_w[idx]) : (unsigned short)0;
        }
        if (idx < OMP_) om_bp[idx] = (idx < OM_) ? om_b[idx] : 0.f;
    }
}

// ---------------------------------------------------------------------------
// Merged GEMM1+GEMM2, R10-proven structure (A-direct + dbuf B staging).
// R12 change: omf output is FP16 (f2h). om values are O(0.01-0.3); fp16
// rel ulp 2^-11 -> py err ~1e-4; bilinear sampling is continuous in py ->
// output perturbation ~1e-5 vs current absmax 9.8e-4. Cuts gemm12 writes
// 50 -> 33.5 MB (omf was its largest byte term).
// grid (256,1,2), block 256 (4 waves), LB(256,2), LDS 32 KB.
// ---------------------------------------------------------------------------
__global__ __launch_bounds__(256, 2) void gemm12_kernel(const unsigned short* __restrict__ xb,
                                                        const unsigned short* __restrict__ omb,
                                                        const unsigned short* __restrict__ vp_wb,
                                                        const unsigned short* __restrict__ om_wb,
                                                        const float* __restrict__ vp_b,
                                                        const float* __restrict__ om_bp,
                                                        unsigned short* __restrict__ valueb,
                                                        unsigned short* __restrict__ omf) {
    __shared__ unsigned short Bs[2][256 * 32];   // 32 KB double-buffered B
    const int which = blockIdx.z;
    const unsigned short* A = which ? omb : xb;
    const unsigned short* B = which ? om_wb : vp_wb;
    const float* bias = which ? om_bp : vp_b;
    const int tid = threadIdx.x;
    const long i0 = (long)blockIdx.x * 128;
    const int nA = (int)(i0 >> 12);          // batch index (128-row blocks never straddle n)
    const int lofs = (int)(i0 & 4095);
    const int wave = tid >> 6, lane = tid & 63;
    const int iw = (wave & 1) * 64, jw = (wave >> 1) * 128;
    const int lm = lane & 15, kq = lane >> 4;
    const int srow = tid >> 2, scol = (tid & 3) * 8;

    frag_cd acc[4][8];
#pragma unroll
    for (int a = 0; a < 4; a++)
#pragma unroll
        for (int c = 0; c < 8; c++) acc[a][c] = (frag_cd){0.f, 0.f, 0.f, 0.f};

    // A-direct lane base (R8-verified): frag = 1 KB contiguous per wave
    const unsigned short* Abase = A + (((size_t)nA * 8) * L_ + lofs + iw + lm) * 32 + kq * 8;
    // B staging source (R6-verified): per-lane row srow, cols scol..scol+7
    const unsigned short* gb0 = B + (long)srow * C_ + scol;

#define STAGE_B(KS, BUF) { \
        const unsigned short* gb_ = gb0 + (KS) * 32; \
        gld16(gb_,             Bs[BUF] + tid * 8); \
        gld16(gb_ + 64 * C_,   Bs[BUF] + 2048 + tid * 8); \
        gld16(gb_ + 128 * C_,  Bs[BUF] + 4096 + tid * 8); \
        gld16(gb_ + 192 * C_,  Bs[BUF] + 6144 + tid * 8); }

    STAGE_B(0, 0)

#pragma unroll
    for (int ks = 0; ks < 8; ks++) {     // k0 = ks*32
        const int buf = ks & 1;
        // drain my wave's gld16 into Bs[buf], then publish across waves
        asm volatile("s_waitcnt vmcnt(0)" ::: "memory");
        __syncthreads();
        if (ks < 7) STAGE_B(ks + 1, buf ^ 1)   // overlaps with MFMA below
        frag_ab af[4], bfr[8];
#pragma unroll
        for (int mi = 0; mi < 4; mi++)
            af[mi] = *(const frag_ab*)(Abase + ((size_t)ks * L_ + mi * 16) * 32);
#pragma unroll
        for (int ni = 0; ni < 8; ni++)
            bfr[ni] = *(const frag_ab*)&Bs[buf][(jw + ni * 16 + lm) * 32 + kq * 8];
#pragma unroll
        for (int mi = 0; mi < 4; mi++)
#pragma unroll
            for (int ni = 0; ni < 8; ni++)
                acc[mi][ni] = __builtin_amdgcn_mfma_f32_16x16x32_bf16(af[mi], bfr[ni], acc[mi][ni], 0, 0, 0);
    }
#undef STAGE_B

    float bv[8];
#pragma unroll
    for (int ni = 0; ni < 8; ni++)
        bv[ni] = bias[jw + ni * 16 + lm];

    const long ibase = i0 + iw + kq * 4;
    const int jbase = jw + lm;
#pragma unroll
    for (int mi = 0; mi < 4; mi++) {
#pragma unroll
        for (int ni = 0; ni < 8; ni++) {
            int jj = jbase + ni * 16;
#pragma unroll
            for (int r = 0; r < 4; r++) {
                long i = ibase + mi * 16 + r;
                float v = acc[mi][ni][r] + bv[ni];
                if (which)
                    omf[i * OMP_ + jj] = f2h(v);    // FP16 om (R12)
                else
                    valueb[i * C_ + jj] = f2h(v);   // FP16 value (fma_mix gather)
            }
        }
    }
}

// ---------------------------------------------------------------------------
// Fused sampling + output projection: R6-proven structure (verified 4x at
// 44.2-44.6 us). R12 change: om is FP16 -> staging halves (two pixel rows =
// 896 B = ONE gld16 issue over 56 lanes; ombuf 7 -> 3.6 KB; LDS 54 KB).
// Tap compute converts fp16->fp32 on read. Everything else byte-identical.
// grid (N, L/64) XCD-pinned, 256 thr / 4 waves, LB(256,2).
// ---------------------------------------------------------------------------
__global__ __launch_bounds__(256, 2) void samplegemm_kernel(const unsigned short* __restrict__ value,
                                                            const __half* __restrict__ om,
                                                            const unsigned short* __restrict__ opw,
                                                            float* __restrict__ out) {
    const int n = blockIdx.x, l0 = blockIdx.y * 64;
    const int tid = threadIdx.x;
    __shared__ __align__(16) unsigned short interm[64 * 256];   // 32 KB, swizzled
    __shared__ __align__(16) __half ombuf[8][224];              // 3.6 KB om stage
    __shared__ float4 wgt[64][9];                               // 9.2 KB
    __shared__ uint4  soff[64][9];                              // 9.2 KB

    const int wave = tid >> 6, lane = tid & 63;
    const int lp = tid >> 2;            // pair 0..63; wave w owns lp 16w..16w+15
    const int g = lp & 7;
    const int c8i = tid & 3;
    const int slot = tid & 31;          // = g*4 + c8i
    const char* vbase = (const char*)(value + (size_t)n * L_ * C_);
    const char* vb = vbase + (size_t)(g * CG_ + c8i * 8) * 2;

    const __half* omn = om + (size_t)n * L_ * OMP_;
    // wave-private om staging: wave w stages pixel rows {2w, 2w+1}, 224 halfs
    // each = 448 B; both rows = 896 B contiguous in ombuf = 56 lanes x 16 B
    // -> ONE gld16 issue (fp16 om halves the staging vs R11).
    __half* obase = &ombuf[2 * wave][0];                // wave-uniform dest base

    const int s0row = (lane < 28) ? 0 : 1;              // 0 -> p0, 1 -> p1
    const int s0idx = (lane < 28) ? lane : (lane - 28); // 16B chunk within row

#define STAGE_OM(REP) { \
        const __half* r0_ = omn + (size_t)(l0 + (REP) * 8 + 2 * wave) * OMP_; \
        if (lane < 56) gld16(r0_ + (size_t)s0row * OMP_ + s0idx * 8, obase); }

    STAGE_OM(0)

    for (int rep = 0; rep < 8; rep++) {
        // gld16 -> LDS dependency is untracked by the compiler: explicit drain.
        asm volatile("s_waitcnt vmcnt(0)" ::: "memory");
        // --- tap compute: 144 items (16 pairs x 9 taps) over 64 lanes ---
#pragma unroll
        for (int j = 0; j < 3; j++) {
            if (!(j == 2 && lane >= 16)) {
                int it = lane + j * 64;                  // 0..143
                int pl_loc = it / 9, k = it - pl_loc * 9;
                int pl = wave * 16 + pl_loc;
                int pic = pl >> 3;                       // pixel-in-chunk 0..7
                const __half* ob2 = &ombuf[pic][(pl & 7) * 27];
                float offy = __half2float(ob2[2 * k]);
                float offx = __half2float(ob2[2 * k + 1]);
                float mk   = __half2float(ob2[18 + k]);
                float4 wq; uint4 sq;
                tapcalc(l0 + rep * 8 + pic, k, offy, offx, mk, wq, sq);
                wgt[pl][k] = wq; soff[pl][k] = sq;
            }
        }
        // order: ombuf ds_reads above stay before the overwriting stage below
        asm volatile("" ::: "memory");
        if (rep < 7) STAGE_OM(rep + 1)
        asm volatile("" ::: "memory");
        // --- gather (table ds_writes -> ds_reads are same-wave, in-order) ---
        const int p = rep * 8 + (lp >> 3);
        float acc[8] = {0.f, 0.f, 0.f, 0.f, 0.f, 0.f, 0.f, 0.f};
#pragma unroll
        for (int k = 0; k < K_; k++) {
            float4 wk = wgt[lp][k];
            uint4  ok = soff[lp][k];
            const uint4 v00 = *(const uint4*)(vb + ok.x);
            const uint4 v01 = *(const uint4*)(vb + ok.y);
            const uint4 v10 = *(const uint4*)(vb + ok.z);
            const uint4 v11 = *(const uint4*)(vb + ok.w);
            // fp16 value: 1 VALU/elem via v_fma_mix_f32 (fpext fused into fma)
#define ACC8(V, WW) { \
            const __half2* h_ = (const __half2*)&V; \
            acc[0] += WW * __half2float(h_[0].x); acc[1] += WW * __half2float(h_[0].y); \
            acc[2] += WW * __half2float(h_[1].x); acc[3] += WW * __half2float(h_[1].y); \
            acc[4] += WW * __half2float(h_[2].x); acc[5] += WW * __half2float(h_[2].y); \
            acc[6] += WW * __half2float(h_[3].x); acc[7] += WW * __half2float(h_[3].y); }
            ACC8(v00, wk.x) ACC8(v01, wk.y) ACC8(v10, wk.z) ACC8(v11, wk.w)
#undef ACC8
        }
        uint4 pk;
        unsigned short* ps = (unsigned short*)&pk;
#pragma unroll
        for (int i = 0; i < 8; i++) ps[i] = f2bf(acc[i]);
        int phys = slot ^ (p & 7);
        *(uint4*)&interm[p * 256 + phys * 8] = pk;      // wave-private rows
    }
#undef STAGE_OM
    __syncthreads();   // the ONLY block barrier: interm ready for phase C

    // --- Phase C: per wave 64q x 64px, 4x4 frags, K=256 in 8 steps ---
    const int lm = lane & 15, kq = lane >> 4;
    const int q0w = wave * 64;
    frag_cd acc2[4][4];
#pragma unroll
    for (int a = 0; a < 4; a++)
#pragma unroll
        for (int c = 0; c < 4; c++) acc2[a][c] = (frag_cd){0.f, 0.f, 0.f, 0.f};

    for (int k0 = 0; k0 < C_; k0 += 32) {
        frag_ab af[4], bfr[4];
#pragma unroll
        for (int mi = 0; mi < 4; mi++)
            af[mi] = *(const frag_ab*)(opw + (size_t)(q0w + mi * 16 + lm) * C_ + k0 + kq * 8);
#pragma unroll
        for (int ni = 0; ni < 4; ni++) {
            int pxr = ni * 16 + lm;
            int phys = (k0 / 8 + kq) ^ (pxr & 7);
            bfr[ni] = *(const frag_ab*)&interm[pxr * 256 + phys * 8];
        }
#pragma unroll
        for (int mi = 0; mi < 4; mi++)
#pragma unroll
            for (int ni = 0; ni < 4; ni++)
                acc2[mi][ni] = __builtin_amdgcn_mfma_f32_16x16x32_bf16(af[mi], bfr[ni], acc2[mi][ni], 0, 0, 0);
    }

    float* ob = out + (size_t)n * C_ * L_ + l0;
#pragma unroll
    for (int mi = 0; mi < 4; mi++) {
#pragma unroll
        for (int ni = 0; ni < 4; ni++) {
            int pxr = ni * 16 + lm;
#pragma unroll
            for (int r = 0; r < 4; r++) {
                int q = q0w + mi * 16 + kq * 4 + r;
                ob[(size_t)q * L_ + pxr] = acc2[mi][ni][r];
            }
        }
    }
}

// ---------------------------------------------------------------------------
// Workspace layout (84,280,320 B total):
//   [0,        16777216)  xb  [n][kb][l][32] bf16 (channel-tiled)
//   [16777216, 33554432)  omb [n][kb][l][32] bf16 (channel-tiled)
//   [33554432, 50331648)  valueb (n,L,C) FP16
//   [50331648, 67108864)  omf (n,L,256) FP16 (R12; was fp32)
//   [83886080, ...)       vp_wb, om_wb, op_wb bf16 (128KB each), om_bp fp32
// ---------------------------------------------------------------------------
extern "C" void kernel_launch(void* const* d_in, const int* in_sizes, int n_in,
                              void* d_out, int out_size, void* d_ws, size_t ws_size,
                              hipStream_t stream) {
    const float* x    = (const float*)d_in[0];
    const float* dw_w = (const float*)d_in[1];
    const float* dw_b = (const float*)d_in[2];
    const float* om_w = (const float*)d_in[3];
    const float* om_b = (const float*)d_in[4];
    const float* vp_w = (const float*)d_in[5];
    const float* vp_b = (const float*)d_in[6];
    const float* op_w = (const float*)d_in[7];
    float* out = (float*)d_out;

    char* ws = (char*)d_ws;
    unsigned short* xb      = (unsigned short*)(ws);
    unsigned short* omb     = (unsigned short*)(ws + 16777216);
    unsigned short* valueb  = (unsigned short*)(ws + 33554432);
    unsigned short* omf     = (unsigned short*)(ws + 50331648);
    unsigned short* vp_wb   = (unsigned short*)(ws + 83886080);
    unsigned short* om_wb   = (unsigned short*)(ws + 84017152);
    unsigned short* op_wb   = (unsigned short*)(ws + 84148224);
    float*          om_bp   = (float*)(ws + 84279296);

    // 1) fused depthwise conv + x transpose + weight conversion (1 row/block,
    //    4 blocks/CU — R2-proven fastest prep)
    prep_kernel<<<dim3(C_ / 32, H_, N_), 256, 0, stream>>>(
        x, dw_w, dw_b, vp_w, om_w, om_b, op_w,
        xb, omb, vp_wb, om_wb, om_bp, op_wb);
    // 2) value = xb @ vp_w^T + vp_b (fp16)  AND  om = omb @ om_w^T + om_b (fp16)
    //    A-direct + double-buffered B-only staging (R10-proven)
    gemm12_kernel<<<dim3(256, 1, 2), 256, 0, stream>>>(
        xb, omb, vp_wb, om_wb, vp_b, om_bp, valueb, omf);
    // 3) fused sampling + output projection -> out (NCHW fp32)
    //    grid (N, L/64): wgid%8 == n pins each batch's value slice to one XCD L2
    samplegemm_kernel<<<dim3(N_, L_ / 64), 256, 0, stream>>>(valueb, (const __half*)omf, op_wb, out);
}